// Round 7
// baseline (742.597 us; speedup 1.0000x reference)
//
#include <hip/hip_runtime.h>

typedef __attribute__((ext_vector_type(8))) short bf16x8;
typedef __attribute__((ext_vector_type(8))) unsigned short u16x8;
typedef __attribute__((ext_vector_type(4))) unsigned short u16x4;
typedef __attribute__((ext_vector_type(4))) float f32x4;
typedef __attribute__((ext_vector_type(2))) unsigned uint2v;

#define DEV static __device__ __forceinline__

DEV unsigned short f2bf(float f){
  unsigned u = __float_as_uint(f);
  u += 0x7fff + ((u>>16)&1);
  return (unsigned short)(u>>16);
}
DEV float bf2f(unsigned short b){ return __uint_as_float(((unsigned)b)<<16); }
DEV unsigned cvtpk(float lo, float hi){
  unsigned r;
  asm("v_cvt_pk_bf16_f32 %0, %1, %2" : "=v"(r) : "v"(lo), "v"(hi));
  return r;
}

DEV void gll16(const void* g, void* l){
  __builtin_amdgcn_global_load_lds((__attribute__((address_space(1))) unsigned*)(void*)g,
                                   (__attribute__((address_space(3))) unsigned*)l, 16, 0, 0);
}

// ---------------- cast fp32 -> bf16 (vectorized) ----------------
__global__ void k_cast(const float* __restrict__ x, unsigned short* __restrict__ y, int n4){
  int i = blockIdx.x*256 + threadIdx.x;
  if (i >= n4) return;
  f32x4 v = ((const f32x4*)x)[i];
  u16x4 o = { f2bf(v.x), f2bf(v.y), f2bf(v.z), f2bf(v.w) };
  ((u16x4*)y)[i] = o;
}

// ---------------- 6-segment weight cast (one launch for all QKV weights) ----------------
__global__ void k_castW(const float* __restrict__ s0, const float* __restrict__ s1,
                        const float* __restrict__ s2, const float* __restrict__ s3,
                        const float* __restrict__ s4, const float* __restrict__ s5,
                        unsigned short* __restrict__ y){
  unsigned i = blockIdx.x*256 + threadIdx.x;          // < 6*2359296
  unsigned seg = i / 2359296u;                        // uniform per block (9216 blocks/seg)
  unsigned off = i - seg*2359296u;
  const float* s = seg==0?s0: seg==1?s1: seg==2?s2: seg==3?s3: seg==4?s4: s5;
  f32x4 v = ((const f32x4*)s)[off];
  u16x4 o = { f2bf(v.x), f2bf(v.y), f2bf(v.z), f2bf(v.w) };
  ((u16x4*)y)[i] = o;
}

// ---------------- QKV projection GEMM with fused RMSNorm+RoPE epilogue ----------------
// sec0 (Q): RMS(nq)+RoPE(qsc) -> Qd ; sec1 (K): RMS(nk)+RoPE -> Kd ; sec2 (V): write Y.
__global__ __launch_bounds__(256) void k_gemmP(
    const unsigned short* __restrict__ X, const unsigned short* __restrict__ W,
    unsigned short* __restrict__ Y,
    const float* __restrict__ b0, const float* __restrict__ b1, const float* __restrict__ b2,
    const float* __restrict__ nqw, const float* __restrict__ nkw,
    const float* __restrict__ cs, const float* __restrict__ sn,
    unsigned short* __restrict__ Qd, unsigned short* __restrict__ Kd,
    int is_img)
{
  const int K = 3072, N = 9216;
  __shared__ unsigned short SH[17408];                // 34816 B: staging (32K) + epilogue scratch
  unsigned short (*As)[4096] = (unsigned short(*)[4096])SH;
  unsigned short (*Bs)[4096] = (unsigned short(*)[4096])(SH + 8192);
  const int t = threadIdx.x, w = t>>6, l = t&63;
  const int li = l&15, g = l>>4;
  const int by = blockIdx.y, bx = blockIdx.x;
  const int sec = by>=48 ? 2 : (by>=24 ? 1 : 0);
  const int hd = by - sec*24;
  const int Cl = hd*128;
  const int R = bx*128;
  const unsigned short* Wp = W + (long)sec*9437184 + (long)Cl*K;
  const float* bias = (sec==0)?b0:(sec==1)?b1:b2;
  const int wr = w>>1, wc = w&1;
  f32x4 acc[4][4] = {};

  auto stage = [&](int buf, int kt){
    const int k0 = kt*32;
    #pragma unroll
    for (int c=0;c<2;c++){
      int row = c*64 + (t>>2);
      int scol = ((t&3)<<3) ^ ((row&3)<<3);           // 4-way XOR pre-swizzle of source
      gll16(X + (long)(R+row)*K + k0 + scol, &As[buf][c*2048 + w*512]);
      gll16(Wp + (long)row*K + k0 + scol, &Bs[buf][c*2048 + w*512]);
    }
  };

  stage(0,0);
  int buf = 0;
  for (int kt=0; kt<96; kt++){
    __syncthreads();
    if (kt+1 < 96) stage(buf^1, kt+1);
    bf16x8 a[4], b[4];
    #pragma unroll
    for (int m=0;m<4;m++){
      int ar = wr*64 + m*16 + li;
      int ac = (g<<3) ^ ((ar&3)<<3);
      a[m] = *(const bf16x8*)&As[buf][ar*32 + ac];
      int br = wc*64 + m*16 + li;
      int bc2 = (g<<3) ^ ((br&3)<<3);
      b[m] = *(const bf16x8*)&Bs[buf][br*32 + bc2];
    }
    #pragma unroll
    for (int m=0;m<4;m++)
      #pragma unroll
      for (int n=0;n<4;n++)
        acc[m][n] = __builtin_amdgcn_mfma_f32_16x16x32_bf16(a[m], b[n], acc[m][n], 0,0,0);
    buf ^= 1;
  }

  float bias_n[4];
  #pragma unroll
  for (int n=0;n<4;n++) bias_n[n] = bias[Cl + wc*64 + n*16 + li];

  if (sec == 2){
    // V: plain Y write (k_ppv transposes later)
    #pragma unroll
    for (int m=0;m<4;m++){
      int row = R + wr*64 + m*16 + (g<<2);
      #pragma unroll
      for (int n=0;n<4;n++){
        long col = (long)by*128 + wc*64 + n*16 + li;
        #pragma unroll
        for (int r=0;r<4;r++)
          Y[(long)(row+r)*N + col] = f2bf(acc[m][n][r] + bias_n[n]);
      }
    }
    return;
  }

  // ---- fused RMSNorm + RoPE epilogue (Q/K) ----
  float part[4][4];
  #pragma unroll
  for (int m=0;m<4;m++)
    #pragma unroll
    for (int r=0;r<4;r++){
      float s_ = 0.f;
      #pragma unroll
      for (int n=0;n<4;n++){ float v = acc[m][n][r] + bias_n[n]; s_ += v*v; }
      part[m][r] = s_;
    }
  #pragma unroll
  for (int m=0;m<4;m++)
    #pragma unroll
    for (int r=0;r<4;r++){
      part[m][r] += __shfl_xor(part[m][r], 1);
      part[m][r] += __shfl_xor(part[m][r], 2);
      part[m][r] += __shfl_xor(part[m][r], 4);
      part[m][r] += __shfl_xor(part[m][r], 8);
    }
  __syncthreads();                                   // staging reads done; reuse SH
  float* rs = (float*)SH;                            // [2 wc][2 wr][64 row]
  if (li == 0){
    #pragma unroll
    for (int m=0;m<4;m++)
      #pragma unroll
      for (int r=0;r<4;r++)
        rs[(wc*2+wr)*64 + m*16 + g*4 + r] = part[m][r];
  }
  __syncthreads();
  float fac[4][4];
  #pragma unroll
  for (int m=0;m<4;m++)
    #pragma unroll
    for (int r=0;r<4;r++){
      int idx = m*16 + g*4 + r;
      float tot = rs[(0*2+wr)*64 + idx] + rs[(1*2+wr)*64 + idx];
      fac[m][r] = rsqrtf(tot*(1.0f/128.0f) + 1e-6f);
    }

  const float* nw = (sec==0) ? nqw : nkw;
  const float qs = (sec==0) ? (float)(0.08838834764831845 * 1.4426950408889634) : 1.0f;
  float nw_n[4];
  #pragma unroll
  for (int n=0;n<4;n++) nw_n[n] = nw[wc*64 + n*16 + li];

  #pragma unroll
  for (int m=0;m<4;m++){
    #pragma unroll
    for (int r=0;r<4;r++){
      int row_l = wr*64 + m*16 + g*4 + r;
      int t_row = R + row_l;
      int b_, s_, p_;
      if (is_img){ b_ = t_row>>10; s_ = t_row&1023; p_ = 512+s_; }
      else       { b_ = t_row>>9;  s_ = t_row&511;  p_ = s_; }
      long didx;
      if (sec==0) didx = (long)(b_*24+hd)*1536 + (is_img ? 512+s_ : s_);
      else        didx = is_img ? ((long)hd*2048 + t_row) : ((long)(b_*24+hd)*512 + s_);
      const float* crow = cs + (long)p_*128;
      const float* srow = sn + (long)p_*128;
      unsigned short* drow = ((sec==0)?Qd:Kd) + didx*128;
      #pragma unroll
      for (int n=0;n<4;n++){
        int cl = wc*64 + n*16 + li;
        float x = (acc[m][n][r] + bias_n[n]) * fac[m][r] * nw_n[n];
        float xo = __shfl_xor(x, 1);
        float o_ = x*crow[cl] + ((l&1) ? xo*srow[cl] : -xo*srow[cl]);
        drow[cl] = f2bf(o_*qs);
      }
    }
  }
}

// ---------------- fused output GEMM (block-diagonal over rows) ----------------
__global__ __launch_bounds__(256) void k_gemmO(
    const unsigned short* __restrict__ X, const unsigned short* __restrict__ Wf,
    float* __restrict__ out, const float* __restrict__ bo, const float* __restrict__ bao)
{
  const int K = 3072;
  __shared__ unsigned short As[2][4096];
  __shared__ unsigned short Bs[2][4096];
  const int t = threadIdx.x, w = t>>6, l = t&63;
  const int bx = blockIdx.x, by = blockIdx.y;
  const bool enc = bx >= 16;
  const unsigned short* Wp = Wf + (enc ? 9437184 : 0);
  const float* bias = enc ? bao : bo;
  const int R = bx*128, C = by*128;
  long xbase, obase;
  if (!enc){ xbase = (long)(R>>10)*1536 + 512 + (R&1023); obase = (long)R*3072; }
  else { int Rp = R-2048; xbase = (long)(Rp>>9)*1536 + (Rp&511); obase = 6291456 + (long)Rp*3072; }
  const int wr = w>>1, wc = w&1;
  f32x4 acc[4][4] = {};

  auto stage = [&](int buf, int kt){
    const int k0 = kt*32;
    #pragma unroll
    for (int c=0;c<2;c++){
      int row = c*64 + (t>>2);
      int scol = ((t&3)<<3) ^ ((row&3)<<3);
      gll16(X + (xbase+row)*K + k0 + scol, &As[buf][c*2048 + w*512]);
      gll16(Wp + (long)(C+row)*K + k0 + scol, &Bs[buf][c*2048 + w*512]);
    }
  };

  stage(0,0);
  int buf = 0;
  for (int kt=0; kt<96; kt++){
    __syncthreads();
    if (kt+1 < 96) stage(buf^1, kt+1);
    bf16x8 a[4], b[4];
    #pragma unroll
    for (int m=0;m<4;m++){
      int ar = wr*64 + m*16 + (l&15);
      int ac = ((l>>4)<<3) ^ ((ar&3)<<3);
      a[m] = *(const bf16x8*)&As[buf][ar*32 + ac];
      int br = wc*64 + m*16 + (l&15);
      int bc2 = ((l>>4)<<3) ^ ((br&3)<<3);
      b[m] = *(const bf16x8*)&Bs[buf][br*32 + bc2];
    }
    #pragma unroll
    for (int m=0;m<4;m++)
      #pragma unroll
      for (int n=0;n<4;n++)
        acc[m][n] = __builtin_amdgcn_mfma_f32_16x16x32_bf16(a[m], b[n], acc[m][n], 0,0,0);
    buf ^= 1;
  }

  #pragma unroll
  for (int m=0;m<4;m++){
    int rl = wr*64 + m*16 + ((l>>4)<<2);
    #pragma unroll
    for (int n=0;n<4;n++){
      int col = C + wc*64 + n*16 + (l&15);
      float bvv = bias[col];
      #pragma unroll
      for (int r=0;r<4;r++)
        out[obase + (long)(rl+r)*3072 + col] = acc[m][n][r] + bvv;
    }
  }
}

// ---------------- V reorder + transpose: Vt[(b,)h][d][j] ----------------
__global__ void k_ppv(const unsigned short* __restrict__ Y, int ystr, int yoff,
                      unsigned short* __restrict__ Vt, int vstr, int no_batch)
{
  __shared__ unsigned short tileS[64][136];
  int t = threadIdx.x, h = blockIdx.y;
  int tile0 = blockIdx.x*64;
  #pragma unroll
  for (int c=0;c<4;c++){
    int j = c*16 + (t>>4), col = (t&15)*8;
    *(u16x8*)&tileS[j][col] = *(const u16x8*)(Y + (long)(tile0+j)*ystr + yoff + h*128 + col);
  }
  __syncthreads();
  int d = t>>1, half = t&1;
  unsigned short tmp[32];
  #pragma unroll
  for (int i=0;i<32;i++) tmp[i] = tileS[half*32+i][d];
  long base;
  if (no_batch) base = ((long)h*128 + d)*vstr + tile0 + half*32;
  else { int b = tile0>>9; base = ((long)(b*24+h)*128 + d)*vstr + (tile0&511) + half*32; }
  #pragma unroll
  for (int k=0;k<4;k++) *(u16x8*)(Vt + base + k*8) = *(const u16x8*)&tmp[k*8];
}

// ---------------- flash attention: 64 Q-rows/block, KV tiles of 64 ----------------
// Full K+V double-buffer, ONE barrier per tile: stages for jt+1 issued right after
// the tile-top barrier, drained at the NEXT tile-top barrier (full tile of compute
// as cover). Ps is wave-private (same-wave LDS is in-order). Swapped QK^T softmax.
__global__ __launch_bounds__(256) void k_attn(
    const unsigned short* __restrict__ Q,
    const unsigned short* __restrict__ Ke, const unsigned short* __restrict__ Ki,
    const unsigned short* __restrict__ Ve, const unsigned short* __restrict__ Vi,
    unsigned short* __restrict__ AO)
{
  __shared__ unsigned short Ks[2][8192];       // [64 kv][128 d], XOR-swizzled
  __shared__ unsigned short Vs[2][8192];       // [128 d][64 kv], XOR-swizzled
  __shared__ unsigned short Ps[4][1408];       // per-wave P tile [16 q][88 k-pad]
  const int t = threadIdx.x, w = t>>6, l = t&63;
  const int h = blockIdx.y, b = blockIdx.z;
  const int bh = b*24 + h;
  const int q0 = blockIdx.x*64 + w*16;
  const int g = l>>4;

  auto stageK = [&](int jt, int bufi){
    const unsigned short* ksrc = (jt < 8) ? Ke + ((long)bh*512 + jt*64)*128
                                          : Ki + ((long)h*2048 + (jt-8)*64)*128;
    #pragma unroll
    for (int c=0;c<4;c++){
      int row = c*16 + (t>>4);
      int col = ((t&15)<<3) ^ ((row&7)<<3);
      gll16(ksrc + row*128 + col, &Ks[bufi][c*2048 + w*512]);
    }
  };
  auto stageV = [&](int jt, int bufi){
    const unsigned short* vsrc; long vstr;
    if (jt < 8){ vsrc = Ve + (long)bh*65536 + jt*64; vstr = 512; }
    else { vsrc = Vi + (long)h*262144 + (jt-8)*64; vstr = 2048; }
    #pragma unroll
    for (int c=0;c<4;c++){
      int row = c*32 + (t>>3);
      int col = ((t&7)<<3) ^ ((row&7)<<3);
      gll16(vsrc + (long)row*vstr + col, &Vs[bufi][c*2048 + w*512]);
    }
  };

  bf16x8 qf[4];
  {
    const unsigned short* qp = Q + ((long)bh*1536 + q0 + (l&15))*128 + (g<<3);
    #pragma unroll
    for (int kc=0;kc<4;kc++) qf[kc] = *(const bf16x8*)(qp + kc*32);
  }
  f32x4 o[8] = {};
  float mx = -1e30f;
  float ls = 0.f;            // per-lane partial sum over own (q, k-slice)

  stageK(0,0); stageV(0,0);
  int buf = 0;
  for (int jt=0; jt<40; jt++){
    __syncthreads();                 // K/V(jt) landed; all waves done with buf^1
    if (jt+1 < 40){ stageK(jt+1, buf^1); stageV(jt+1, buf^1); }

    // S^T tile: sf[ct][r] = S[q = q0 + (l&15)][k = ct*16 + g*4 + r]
    f32x4 sf[4];
    __builtin_amdgcn_s_setprio(1);
    #pragma unroll
    for (int ct=0;ct<4;ct++){
      f32x4 s = {};
      #pragma unroll
      for (int kc=0;kc<4;kc++){
        int krow = ct*16 + (l&15);
        int kcol = (kc*32 + (g<<3)) ^ ((krow&7)<<3);
        bf16x8 kb = *(const bf16x8*)&Ks[buf][krow*128 + kcol];
        s = __builtin_amdgcn_mfma_f32_16x16x32_bf16(kb, qf[kc], s, 0,0,0);  // SWAPPED
      }
      sf[ct] = s;
    }
    __builtin_amdgcn_s_setprio(0);

    // per-lane slice max (own q); defer-max with THR=8 (log2 domain)
    float pm = sf[0][0];
    #pragma unroll
    for (int ct=0;ct<4;ct++)
      #pragma unroll
      for (int r=0;r<4;r++) pm = fmaxf(pm, sf[ct][r]);
    if (!__all(pm <= mx + 8.0f)){
      float tmax = pm;
      tmax = fmaxf(tmax, __shfl_xor(tmax, 16));
      tmax = fmaxf(tmax, __shfl_xor(tmax, 32));     // full-row max for own q
      float mn = fmaxf(mx, tmax);
      float al = exp2f(mx - mn);
      mx = mn;
      ls *= al;
      #pragma unroll
      for (int r=0;r<4;r++){
        float alo = __shfl(al, (l&48) | ((g<<2)+r));  // factor for o-row q' = 4g+r
        #pragma unroll
        for (int f=0;f<8;f++) o[f][r] *= alo;
      }
    }
    // P = exp2(S - mx), pack pairs, write b64; accumulate per-lane ls
    #pragma unroll
    for (int ct=0;ct<4;ct++){
      float p0 = exp2f(sf[ct][0]-mx), p1 = exp2f(sf[ct][1]-mx);
      float p2 = exp2f(sf[ct][2]-mx), p3 = exp2f(sf[ct][3]-mx);
      ls += (p0+p1)+(p2+p3);
      uint2v pk = { cvtpk(p0,p1), cvtpk(p2,p3) };
      *(uint2v*)&Ps[w][(l&15)*88 + ct*16 + (g<<2)] = pk;
    }
    asm volatile("" ::: "memory");   // keep ds_write->ds_read program order

    bf16x8 pa[2];
    #pragma unroll
    for (int kc=0;kc<2;kc++)
      pa[kc] = *(const bf16x8*)&Ps[w][(l&15)*88 + kc*32 + (g<<3)];
    __builtin_amdgcn_s_setprio(1);
    #pragma unroll
    for (int f=0;f<8;f++){
      #pragma unroll
      for (int kc=0;kc<2;kc++){
        int vrow = f*16 + (l&15);
        int vcol = (kc*32 + (g<<3)) ^ ((vrow&7)<<3);
        bf16x8 vb = *(const bf16x8*)&Vs[buf][vrow*64 + vcol];
        o[f] = __builtin_amdgcn_mfma_f32_16x16x32_bf16(pa[kc], vb, o[f], 0,0,0);
      }
    }
    __builtin_amdgcn_s_setprio(0);
    buf ^= 1;
  }

  // finalize: full row-sum for own q, then fetch for o-rows q' = 4g+r
  ls += __shfl_xor(ls, 16);
  ls += __shfl_xor(ls, 32);
  #pragma unroll
  for (int r=0;r<4;r++){
    float lso = __shfl(ls, (l&48) | ((g<<2)+r));
    float inv = 1.0f/lso;
    int qrow = q0 + (g<<2) + r;
    #pragma unroll
    for (int f=0;f<8;f++){
      AO[((long)b*1536 + qrow)*3072 + h*128 + f*16 + (l&15)] = f2bf(o[f][r]*inv);
    }
  }
}

// ---------------- host launch ----------------
extern "C" void kernel_launch(void* const* d_in, const int* in_sizes, int n_in,
                              void* d_out, int out_size, void* d_ws, size_t ws_size,
                              hipStream_t stream)
{
  const float* hs  = (const float*)d_in[0];
  const float* ehs = (const float*)d_in[1];
  const float* rc  = (const float*)d_in[2];
  const float* rs_ = (const float*)d_in[3];
  const float* wq = (const float*)d_in[4];  const float* bq = (const float*)d_in[5];
  const float* wk = (const float*)d_in[6];  const float* bk = (const float*)d_in[7];
  const float* wv = (const float*)d_in[8];  const float* bv = (const float*)d_in[9];
  const float* waq= (const float*)d_in[10]; const float* baq= (const float*)d_in[11];
  const float* wak= (const float*)d_in[12]; const float* bak= (const float*)d_in[13];
  const float* wav= (const float*)d_in[14]; const float* bav= (const float*)d_in[15];
  const float* wo = (const float*)d_in[16]; const float* bo = (const float*)d_in[17];
  const float* wao= (const float*)d_in[18]; const float* bao= (const float*)d_in[19];
  const float* nq = (const float*)d_in[20]; const float* nk = (const float*)d_in[21];
  const float* naq= (const float*)d_in[22]; const float* nak= (const float*)d_in[23];

  char* p = (char*)d_ws;
  auto alloc = [&](size_t bytes){ char* r = p; p += bytes; return r; };

  if (ws_size >= (size_t)245366784){
    // ---------- main path (245.4 MB; confirmed available) ----------
    unsigned short* Xh = (unsigned short*)alloc(12582912);  // [2048][3072]
    unsigned short* Xe = (unsigned short*)alloc(6291456);   // [1024][3072]
    unsigned short* Wb = (unsigned short*)alloc(113246208); // 6 weight slots bf16
    unsigned short* Yb = (unsigned short*)alloc(56623104);  // [3072][9216] (V section only)
    unsigned short* Qb = (unsigned short*)alloc(18874368);  // Q [2][24][1536][128]
    unsigned short* Ke = (unsigned short*)alloc(6291456);   // Kenc [2][24][512][128]
    unsigned short* Ki = (unsigned short*)alloc(12582912);  // Kimg [24][2048][128]
    unsigned short* Ve = (unsigned short*)alloc(6291456);   // Vtenc [2][24][128][512]
    unsigned short* Vi = (unsigned short*)alloc(12582912);  // Vtimg [24][128][2048]
    unsigned short* AO = Xh;                                // aliases Xh+Xe (dead by attn)
    unsigned short* Ye = Yb + (long)18874368;               // enc proj rows

    k_cast<<<6144,256,0,stream>>>(hs, Xh, 1572864);
    k_cast<<<3072,256,0,stream>>>(ehs, Xe, 786432);
    k_castW<<<55296,256,0,stream>>>(wq, wk, wv, waq, wak, wav, Wb);

    k_gemmP<<<dim3(16,72),256,0,stream>>>(Xh, Wb, Yb, bq, bk, bv,
                                          nq, nk, rc, rs_, Qb, Ki, 1);
    k_gemmP<<<dim3(8,72),256,0,stream>>>(Xe, Wb + 28311552, Ye, baq, bak, bav,
                                         naq, nak, rc, rs_, Qb, Ke, 0);

    k_ppv<<<dim3(32,24),256,0,stream>>>(Yb, 9216, 6144, Vi, 2048, 1);
    k_ppv<<<dim3(16,24),256,0,stream>>>(Ye, 9216, 6144, Ve, 512, 0);

    k_attn<<<dim3(24,24,2),256,0,stream>>>(Qb, Ke, Ki, Ve, Vi, AO);

    k_cast<<<9216,256,0,stream>>>(wo,  Wb, 2359296);
    k_cast<<<9216,256,0,stream>>>(wao, Wb + 9437184, 2359296);
    k_gemmO<<<dim3(24,24),256,0,stream>>>(AO, Wb, (float*)d_out, bo, bao);
  } else {
    // ---------- fallback path (132.1 MB): 3 weight slots, groups sequential ----------
    unsigned short* Xh = (unsigned short*)alloc(12582912);
    unsigned short* Xe = (unsigned short*)alloc(6291456);
    unsigned short* Wb = (unsigned short*)alloc(56623104);  // 3 slots
    unsigned short* Yb = (unsigned short*)alloc(37748736);  // [2048][9216] (V section only)
    unsigned short* Qb = (unsigned short*)alloc(18874368);
    unsigned short* Ke = (unsigned short*)alloc(6291456);
    unsigned short* Ki = (unsigned short*)alloc(12582912);
    unsigned short* Ve = (unsigned short*)alloc(6291456);
    unsigned short* Vi = (unsigned short*)alloc(12582912);
    unsigned short* AO = Xh;

    k_cast<<<6144,256,0,stream>>>(hs, Xh, 1572864);
    k_cast<<<3072,256,0,stream>>>(ehs, Xe, 786432);

    k_cast<<<9216,256,0,stream>>>(wq, Wb, 2359296);
    k_cast<<<9216,256,0,stream>>>(wk, Wb + 9437184, 2359296);
    k_cast<<<9216,256,0,stream>>>(wv, Wb + 18874368, 2359296);
    k_gemmP<<<dim3(16,72),256,0,stream>>>(Xh, Wb, Yb, bq, bk, bv,
                                          nq, nk, rc, rs_, Qb, Ki, 1);
    k_ppv<<<dim3(32,24),256,0,stream>>>(Yb, 9216, 6144, Vi, 2048, 1);

    k_cast<<<9216,256,0,stream>>>(waq, Wb, 2359296);
    k_cast<<<9216,256,0,stream>>>(wak, Wb + 9437184, 2359296);
    k_cast<<<9216,256,0,stream>>>(wav, Wb + 18874368, 2359296);
    k_gemmP<<<dim3(8,72),256,0,stream>>>(Xe, Wb, Yb, baq, bak, bav,
                                         naq, nak, rc, rs_, Qb, Ke, 0);
    k_ppv<<<dim3(16,24),256,0,stream>>>(Yb, 9216, 6144, Ve, 512, 0);

    k_attn<<<dim3(24,24,2),256,0,stream>>>(Qb, Ke, Ki, Ve, Vi, AO);

    k_cast<<<9216,256,0,stream>>>(wo,  Wb, 2359296);
    k_cast<<<9216,256,0,stream>>>(wao, Wb + 9437184, 2359296);
    k_gemmO<<<dim3(24,24),256,0,stream>>>(AO, Wb, (float*)d_out, bo, bao);
  }
}

// Round 8
// 694.804 us; speedup vs baseline: 1.0688x; 1.0688x over previous
//
#include <hip/hip_runtime.h>

typedef __attribute__((ext_vector_type(8))) short bf16x8;
typedef __attribute__((ext_vector_type(8))) unsigned short u16x8;
typedef __attribute__((ext_vector_type(4))) unsigned short u16x4;
typedef __attribute__((ext_vector_type(4))) float f32x4;
typedef __attribute__((ext_vector_type(2))) unsigned uint2v;

#define DEV static __device__ __forceinline__

DEV unsigned short f2bf(float f){
  unsigned u = __float_as_uint(f);
  u += 0x7fff + ((u>>16)&1);
  return (unsigned short)(u>>16);
}
DEV float bf2f(unsigned short b){ return __uint_as_float(((unsigned)b)<<16); }
DEV unsigned cvtpk(float lo, float hi){
  unsigned r;
  asm("v_cvt_pk_bf16_f32 %0, %1, %2" : "=v"(r) : "v"(lo), "v"(hi));
  return r;
}

DEV void gll16(const void* g, void* l){
  __builtin_amdgcn_global_load_lds((__attribute__((address_space(1))) unsigned*)(void*)g,
                                   (__attribute__((address_space(3))) unsigned*)l, 16, 0, 0);
}

// ---------------- cast fp32 -> bf16 (vectorized) ----------------
__global__ void k_cast(const float* __restrict__ x, unsigned short* __restrict__ y, int n4){
  int i = blockIdx.x*256 + threadIdx.x;
  if (i >= n4) return;
  f32x4 v = ((const f32x4*)x)[i];
  u16x4 o = { f2bf(v.x), f2bf(v.y), f2bf(v.z), f2bf(v.w) };
  ((u16x4*)y)[i] = o;
}

// ---------------- 6-segment weight cast ----------------
__global__ void k_castW(const float* __restrict__ s0, const float* __restrict__ s1,
                        const float* __restrict__ s2, const float* __restrict__ s3,
                        const float* __restrict__ s4, const float* __restrict__ s5,
                        unsigned short* __restrict__ y){
  unsigned i = blockIdx.x*256 + threadIdx.x;          // < 6*2359296
  unsigned seg = i / 2359296u;
  unsigned off = i - seg*2359296u;
  const float* s = seg==0?s0: seg==1?s1: seg==2?s2: seg==3?s3: seg==4?s4: s5;
  f32x4 v = ((const f32x4*)s)[off];
  u16x4 o = { f2bf(v.x), f2bf(v.y), f2bf(v.z), f2bf(v.w) };
  ((u16x4*)y)[i] = o;
}

// ---------------- 2-segment weight cast (wo/wao) ----------------
__global__ void k_castW2(const float* __restrict__ s0, const float* __restrict__ s1,
                         unsigned short* __restrict__ y){
  unsigned i = blockIdx.x*256 + threadIdx.x;          // < 2*2359296
  unsigned seg = i / 2359296u;
  unsigned off = i - seg*2359296u;
  const float* s = seg==0?s0:s1;
  f32x4 v = ((const f32x4*)s)[off];
  u16x4 o = { f2bf(v.x), f2bf(v.y), f2bf(v.z), f2bf(v.w) };
  ((u16x4*)y)[i] = o;
}

// ---------------- QKV projection GEMM, fully fused epilogues ----------------
// sec0 (Q): RMS(nq)+RoPE(qsc) -> Qd ; sec1 (K): RMS(nk)+RoPE -> Kd ;
// sec2 (V): LDS-transpose -> Vd[(b,)h][d][tok] directly (no Y round-trip).
__global__ __launch_bounds__(256) void k_gemmP(
    const unsigned short* __restrict__ X, const unsigned short* __restrict__ W,
    const float* __restrict__ b0, const float* __restrict__ b1, const float* __restrict__ b2,
    const float* __restrict__ nqw, const float* __restrict__ nkw,
    const float* __restrict__ cs, const float* __restrict__ sn,
    unsigned short* __restrict__ Qd, unsigned short* __restrict__ Kd,
    unsigned short* __restrict__ Vd,
    int is_img)
{
  const int K = 3072;
  __shared__ unsigned short SH[17408];                // 34816 B: staging (32K) / epilogue scratch
  unsigned short (*As)[4096] = (unsigned short(*)[4096])SH;
  unsigned short (*Bs)[4096] = (unsigned short(*)[4096])(SH + 8192);
  const int t = threadIdx.x, w = t>>6, l = t&63;
  const int li = l&15, g = l>>4;
  const int by = blockIdx.y, bx = blockIdx.x;
  const int sec = by>=48 ? 2 : (by>=24 ? 1 : 0);
  const int hd = by - sec*24;
  const int Cl = hd*128;
  const int R = bx*128;
  const unsigned short* Wp = W + (long)sec*9437184 + (long)Cl*K;
  const float* bias = (sec==0)?b0:(sec==1)?b1:b2;
  const int wr = w>>1, wc = w&1;
  f32x4 acc[4][4] = {};

  auto stage = [&](int buf, int kt){
    const int k0 = kt*32;
    #pragma unroll
    for (int c=0;c<2;c++){
      int row = c*64 + (t>>2);
      int scol = ((t&3)<<3) ^ ((row&3)<<3);           // 4-way XOR pre-swizzle of source
      gll16(X + (long)(R+row)*K + k0 + scol, &As[buf][c*2048 + w*512]);
      gll16(Wp + (long)row*K + k0 + scol, &Bs[buf][c*2048 + w*512]);
    }
  };

  stage(0,0);
  int buf = 0;
  for (int kt=0; kt<96; kt++){
    __syncthreads();
    if (kt+1 < 96) stage(buf^1, kt+1);
    bf16x8 a[4], b[4];
    #pragma unroll
    for (int m=0;m<4;m++){
      int ar = wr*64 + m*16 + li;
      int ac = (g<<3) ^ ((ar&3)<<3);
      a[m] = *(const bf16x8*)&As[buf][ar*32 + ac];
      int br = wc*64 + m*16 + li;
      int bc2 = (g<<3) ^ ((br&3)<<3);
      b[m] = *(const bf16x8*)&Bs[buf][br*32 + bc2];
    }
    #pragma unroll
    for (int m=0;m<4;m++)
      #pragma unroll
      for (int n=0;n<4;n++)
        acc[m][n] = __builtin_amdgcn_mfma_f32_16x16x32_bf16(a[m], b[n], acc[m][n], 0,0,0);
    buf ^= 1;
  }

  float bias_n[4];
  #pragma unroll
  for (int n=0;n<4;n++) bias_n[n] = bias[Cl + wc*64 + n*16 + li];

  if (sec == 2){
    // ---- V: LDS-transpose epilogue, direct Vt write ----
    __syncthreads();                                  // all waves done reading As/Bs
    unsigned short* SHT = SH;                         // [128 d][136 tok] (16B-aligned rows)
    #pragma unroll
    for (int m=0;m<4;m++){
      int tok_l = wr*64 + m*16 + (g<<2);
      #pragma unroll
      for (int n=0;n<4;n++){
        int col_l = wc*64 + n*16 + li;
        u16x4 v4 = { f2bf(acc[m][n][0]+bias_n[n]), f2bf(acc[m][n][1]+bias_n[n]),
                     f2bf(acc[m][n][2]+bias_n[n]), f2bf(acc[m][n][3]+bias_n[n]) };
        *(u16x4*)&SHT[col_l*136 + tok_l] = v4;
      }
    }
    __syncthreads();
    int d = t>>1, half = t&1;
    int tok0 = R + half*64;
    long base;
    if (is_img) base = ((long)hd*128 + d)*2048 + tok0;
    else { int b_ = tok0>>9, s_ = tok0&511; base = ((long)(b_*24+hd)*128 + d)*512 + s_; }
    #pragma unroll
    for (int k2=0;k2<8;k2++)
      *(u16x8*)(Vd + base + k2*8) = *(const u16x8*)&SHT[d*136 + half*64 + k2*8];
    return;
  }

  // ---- fused RMSNorm + RoPE epilogue (Q/K) ----
  float part[4][4];
  #pragma unroll
  for (int m=0;m<4;m++)
    #pragma unroll
    for (int r=0;r<4;r++){
      float s_ = 0.f;
      #pragma unroll
      for (int n=0;n<4;n++){ float v = acc[m][n][r] + bias_n[n]; s_ += v*v; }
      part[m][r] = s_;
    }
  #pragma unroll
  for (int m=0;m<4;m++)
    #pragma unroll
    for (int r=0;r<4;r++){
      part[m][r] += __shfl_xor(part[m][r], 1);
      part[m][r] += __shfl_xor(part[m][r], 2);
      part[m][r] += __shfl_xor(part[m][r], 4);
      part[m][r] += __shfl_xor(part[m][r], 8);
    }
  __syncthreads();                                   // staging reads done; reuse SH
  float* rs = (float*)SH;                            // [2 wc][2 wr][64 row]
  if (li == 0){
    #pragma unroll
    for (int m=0;m<4;m++)
      #pragma unroll
      for (int r=0;r<4;r++)
        rs[(wc*2+wr)*64 + m*16 + g*4 + r] = part[m][r];
  }
  __syncthreads();
  float fac[4][4];
  #pragma unroll
  for (int m=0;m<4;m++)
    #pragma unroll
    for (int r=0;r<4;r++){
      int idx = m*16 + g*4 + r;
      float tot = rs[(0*2+wr)*64 + idx] + rs[(1*2+wr)*64 + idx];
      fac[m][r] = rsqrtf(tot*(1.0f/128.0f) + 1e-6f);
    }

  const float* nw = (sec==0) ? nqw : nkw;
  const float qs = (sec==0) ? (float)(0.08838834764831845 * 1.4426950408889634) : 1.0f;
  float nw_n[4];
  #pragma unroll
  for (int n=0;n<4;n++) nw_n[n] = nw[wc*64 + n*16 + li];

  #pragma unroll
  for (int m=0;m<4;m++){
    #pragma unroll
    for (int r=0;r<4;r++){
      int row_l = wr*64 + m*16 + g*4 + r;
      int t_row = R + row_l;
      int b_, s_, p_;
      if (is_img){ b_ = t_row>>10; s_ = t_row&1023; p_ = 512+s_; }
      else       { b_ = t_row>>9;  s_ = t_row&511;  p_ = s_; }
      long didx;
      if (sec==0) didx = (long)(b_*24+hd)*1536 + (is_img ? 512+s_ : s_);
      else        didx = is_img ? ((long)hd*2048 + t_row) : ((long)(b_*24+hd)*512 + s_);
      const float* crow = cs + (long)p_*128;
      const float* srow = sn + (long)p_*128;
      unsigned short* drow = ((sec==0)?Qd:Kd) + didx*128;
      #pragma unroll
      for (int n=0;n<4;n++){
        int cl = wc*64 + n*16 + li;
        float x = (acc[m][n][r] + bias_n[n]) * fac[m][r] * nw_n[n];
        float xo = __shfl_xor(x, 1);
        float o_ = x*crow[cl] + ((l&1) ? xo*srow[cl] : -xo*srow[cl]);
        drow[cl] = f2bf(o_*qs);
      }
    }
  }
}

// ---------------- fused output GEMM (block-diagonal over rows) ----------------
__global__ __launch_bounds__(256) void k_gemmO(
    const unsigned short* __restrict__ X, const unsigned short* __restrict__ Wf,
    float* __restrict__ out, const float* __restrict__ bo, const float* __restrict__ bao)
{
  const int K = 3072;
  __shared__ unsigned short As[2][4096];
  __shared__ unsigned short Bs[2][4096];
  const int t = threadIdx.x, w = t>>6, l = t&63;
  const int bx = blockIdx.x, by = blockIdx.y;
  const bool enc = bx >= 16;
  const unsigned short* Wp = Wf + (enc ? 9437184 : 0);
  const float* bias = enc ? bao : bo;
  const int R = bx*128, C = by*128;
  long xbase, obase;
  if (!enc){ xbase = (long)(R>>10)*1536 + 512 + (R&1023); obase = (long)R*3072; }
  else { int Rp = R-2048; xbase = (long)(Rp>>9)*1536 + (Rp&511); obase = 6291456 + (long)Rp*3072; }
  const int wr = w>>1, wc = w&1;
  f32x4 acc[4][4] = {};

  auto stage = [&](int buf, int kt){
    const int k0 = kt*32;
    #pragma unroll
    for (int c=0;c<2;c++){
      int row = c*64 + (t>>2);
      int scol = ((t&3)<<3) ^ ((row&3)<<3);
      gll16(X + (xbase+row)*K + k0 + scol, &As[buf][c*2048 + w*512]);
      gll16(Wp + (long)(C+row)*K + k0 + scol, &Bs[buf][c*2048 + w*512]);
    }
  };

  stage(0,0);
  int buf = 0;
  for (int kt=0; kt<96; kt++){
    __syncthreads();
    if (kt+1 < 96) stage(buf^1, kt+1);
    bf16x8 a[4], b[4];
    #pragma unroll
    for (int m=0;m<4;m++){
      int ar = wr*64 + m*16 + (l&15);
      int ac = ((l>>4)<<3) ^ ((ar&3)<<3);
      a[m] = *(const bf16x8*)&As[buf][ar*32 + ac];
      int br = wc*64 + m*16 + (l&15);
      int bc2 = ((l>>4)<<3) ^ ((br&3)<<3);
      b[m] = *(const bf16x8*)&Bs[buf][br*32 + bc2];
    }
    #pragma unroll
    for (int m=0;m<4;m++)
      #pragma unroll
      for (int n=0;n<4;n++)
        acc[m][n] = __builtin_amdgcn_mfma_f32_16x16x32_bf16(a[m], b[n], acc[m][n], 0,0,0);
    buf ^= 1;
  }

  #pragma unroll
  for (int m=0;m<4;m++){
    int rl = wr*64 + m*16 + ((l>>4)<<2);
    #pragma unroll
    for (int n=0;n<4;n++){
      int col = C + wc*64 + n*16 + (l&15);
      float bvv = bias[col];
      #pragma unroll
      for (int r=0;r<4;r++)
        out[obase + (long)(rl+r)*3072 + col] = acc[m][n][r] + bvv;
    }
  }
}

// ---------------- flash attention (round-6 proven schedule) ----------------
// Single-buffered K/V, 2 barriers/tile; stageV at tile top (covered by QK+softmax),
// stageK(jt+1) after mid barrier (covered by PV). Swapped QK^T softmax.
__global__ __launch_bounds__(256) void k_attn(
    const unsigned short* __restrict__ Q,
    const unsigned short* __restrict__ Ke, const unsigned short* __restrict__ Ki,
    const unsigned short* __restrict__ Ve, const unsigned short* __restrict__ Vi,
    unsigned short* __restrict__ AO)
{
  __shared__ unsigned short Ks[8192];          // [64 kv][128 d], XOR-swizzled
  __shared__ unsigned short Vs[8192];          // [128 d][64 kv], XOR-swizzled
  __shared__ unsigned short Ps[4][1408];       // per-wave P tile [16 q][88 k-pad]
  const int t = threadIdx.x, w = t>>6, l = t&63;
  const int h = blockIdx.y, b = blockIdx.z;
  const int bh = b*24 + h;
  const int q0 = blockIdx.x*64 + w*16;
  const int g = l>>4;

  auto stageK = [&](int jt){
    const unsigned short* ksrc = (jt < 8) ? Ke + ((long)bh*512 + jt*64)*128
                                          : Ki + ((long)h*2048 + (jt-8)*64)*128;
    #pragma unroll
    for (int c=0;c<4;c++){
      int row = c*16 + (t>>4);
      int col = ((t&15)<<3) ^ ((row&7)<<3);
      gll16(ksrc + row*128 + col, &Ks[c*2048 + w*512]);
    }
  };
  auto stageV = [&](int jt){
    const unsigned short* vsrc; long vstr;
    if (jt < 8){ vsrc = Ve + (long)bh*65536 + jt*64; vstr = 512; }
    else { vsrc = Vi + (long)h*262144 + (jt-8)*64; vstr = 2048; }
    #pragma unroll
    for (int c=0;c<4;c++){
      int row = c*32 + (t>>3);
      int col = ((t&7)<<3) ^ ((row&7)<<3);
      gll16(vsrc + (long)row*vstr + col, &Vs[c*2048 + w*512]);
    }
  };

  bf16x8 qf[4];
  {
    const unsigned short* qp = Q + ((long)bh*1536 + q0 + (l&15))*128 + (g<<3);
    #pragma unroll
    for (int kc=0;kc<4;kc++) qf[kc] = *(const bf16x8*)(qp + kc*32);
  }
  f32x4 o[8] = {};
  float mx = -1e30f;
  float ls = 0.f;            // per-lane partial sum over own (q, k-slice)

  stageK(0);
  for (int jt=0; jt<40; jt++){
    __syncthreads();                 // K(jt) landed; all waves past PV(jt-1)
    stageV(jt);                      // covered by QK + softmax below

    // S^T tile: sf[ct][r] = S[q = q0 + (l&15)][k = ct*16 + g*4 + r]
    f32x4 sf[4];
    __builtin_amdgcn_s_setprio(1);
    #pragma unroll
    for (int ct=0;ct<4;ct++){
      f32x4 s = {};
      #pragma unroll
      for (int kc=0;kc<4;kc++){
        int krow = ct*16 + (l&15);
        int kcol = (kc*32 + (g<<3)) ^ ((krow&7)<<3);
        bf16x8 kb = *(const bf16x8*)&Ks[krow*128 + kcol];
        s = __builtin_amdgcn_mfma_f32_16x16x32_bf16(kb, qf[kc], s, 0,0,0);  // SWAPPED
      }
      sf[ct] = s;
    }
    __builtin_amdgcn_s_setprio(0);

    // per-lane slice max (own q); defer-max with THR=8 (log2 domain)
    float pm = sf[0][0];
    #pragma unroll
    for (int ct=0;ct<4;ct++)
      #pragma unroll
      for (int r=0;r<4;r++) pm = fmaxf(pm, sf[ct][r]);
    if (!__all(pm <= mx + 8.0f)){
      float tmax = pm;
      tmax = fmaxf(tmax, __shfl_xor(tmax, 16));
      tmax = fmaxf(tmax, __shfl_xor(tmax, 32));     // full-row max for own q
      float mn = fmaxf(mx, tmax);
      float al = exp2f(mx - mn);
      mx = mn;
      ls *= al;
      #pragma unroll
      for (int r=0;r<4;r++){
        float alo = __shfl(al, (l&48) | ((g<<2)+r));  // factor for o-row q' = 4g+r
        #pragma unroll
        for (int f=0;f<8;f++) o[f][r] *= alo;
      }
    }
    // P = exp2(S - mx), pack pairs, write b64; accumulate per-lane ls
    #pragma unroll
    for (int ct=0;ct<4;ct++){
      float p0 = exp2f(sf[ct][0]-mx), p1 = exp2f(sf[ct][1]-mx);
      float p2 = exp2f(sf[ct][2]-mx), p3 = exp2f(sf[ct][3]-mx);
      ls += (p0+p1)+(p2+p3);
      uint2v pk = { cvtpk(p0,p1), cvtpk(p2,p3) };
      *(uint2v*)&Ps[w][(l&15)*88 + ct*16 + (g<<2)] = pk;
    }
    __syncthreads();                 // V(jt) landed; all waves done reading Ks

    if (jt+1 < 40) stageK(jt+1);     // overwrites Ks; covered by PV below

    bf16x8 pa[2];
    #pragma unroll
    for (int kc=0;kc<2;kc++)
      pa[kc] = *(const bf16x8*)&Ps[w][(l&15)*88 + kc*32 + (g<<3)];
    __builtin_amdgcn_s_setprio(1);
    #pragma unroll
    for (int f=0;f<8;f++){
      #pragma unroll
      for (int kc=0;kc<2;kc++){
        int vrow = f*16 + (l&15);
        int vcol = (kc*32 + (g<<3)) ^ ((vrow&7)<<3);
        bf16x8 vb = *(const bf16x8*)&Vs[vrow*64 + vcol];
        o[f] = __builtin_amdgcn_mfma_f32_16x16x32_bf16(pa[kc], vb, o[f], 0,0,0);
      }
    }
    __builtin_amdgcn_s_setprio(0);
  }

  // finalize: full row-sum for own q, then fetch for o-rows q' = 4g+r
  ls += __shfl_xor(ls, 16);
  ls += __shfl_xor(ls, 32);
  #pragma unroll
  for (int r=0;r<4;r++){
    float lso = __shfl(ls, (l&48) | ((g<<2)+r));
    float inv = 1.0f/lso;
    int qrow = q0 + (g<<2) + r;
    #pragma unroll
    for (int f=0;f<8;f++){
      AO[((long)b*1536 + qrow)*3072 + h*128 + f*16 + (l&15)] = f2bf(o[f][r]*inv);
    }
  }
}

// ---------------- host launch ----------------
extern "C" void kernel_launch(void* const* d_in, const int* in_sizes, int n_in,
                              void* d_out, int out_size, void* d_ws, size_t ws_size,
                              hipStream_t stream)
{
  const float* hs  = (const float*)d_in[0];
  const float* ehs = (const float*)d_in[1];
  const float* rc  = (const float*)d_in[2];
  const float* rs_ = (const float*)d_in[3];
  const float* wq = (const float*)d_in[4];  const float* bq = (const float*)d_in[5];
  const float* wk = (const float*)d_in[6];  const float* bk = (const float*)d_in[7];
  const float* wv = (const float*)d_in[8];  const float* bv = (const float*)d_in[9];
  const float* waq= (const float*)d_in[10]; const float* baq= (const float*)d_in[11];
  const float* wak= (const float*)d_in[12]; const float* bak= (const float*)d_in[13];
  const float* wav= (const float*)d_in[14]; const float* bav= (const float*)d_in[15];
  const float* wo = (const float*)d_in[16]; const float* bo = (const float*)d_in[17];
  const float* wao= (const float*)d_in[18]; const float* bao= (const float*)d_in[19];
  const float* nq = (const float*)d_in[20]; const float* nk = (const float*)d_in[21];
  const float* naq= (const float*)d_in[22]; const float* nak= (const float*)d_in[23];

  char* p = (char*)d_ws;
  auto alloc = [&](size_t bytes){ char* r = p; p += bytes; return r; };

  if (ws_size >= (size_t)188743680){
    // ---------- main path (188.7 MB) ----------
    unsigned short* Xh = (unsigned short*)alloc(12582912);  // [2048][3072]
    unsigned short* Xe = (unsigned short*)alloc(6291456);   // [1024][3072]
    unsigned short* Wb = (unsigned short*)alloc(113246208); // 6 weight slots bf16
    unsigned short* Qb = (unsigned short*)alloc(18874368);  // Q [2][24][1536][128]
    unsigned short* Ke = (unsigned short*)alloc(6291456);   // Kenc [2][24][512][128]
    unsigned short* Ki = (unsigned short*)alloc(12582912);  // Kimg [24][2048][128]
    unsigned short* Ve = (unsigned short*)alloc(6291456);   // Vtenc [2][24][128][512]
    unsigned short* Vi = (unsigned short*)alloc(12582912);  // Vtimg [24][128][2048]
    unsigned short* AO = Xh;                                // aliases Xh+Xe (dead by attn)

    k_cast<<<6144,256,0,stream>>>(hs, Xh, 1572864);
    k_cast<<<3072,256,0,stream>>>(ehs, Xe, 786432);
    k_castW<<<55296,256,0,stream>>>(wq, wk, wv, waq, wak, wav, Wb);

    k_gemmP<<<dim3(16,72),256,0,stream>>>(Xh, Wb, bq, bk, bv,
                                          nq, nk, rc, rs_, Qb, Ki, Vi, 1);
    k_gemmP<<<dim3(8,72),256,0,stream>>>(Xe, Wb + 28311552, baq, bak, bav,
                                         naq, nak, rc, rs_, Qb, Ke, Ve, 0);

    k_attn<<<dim3(24,24,2),256,0,stream>>>(Qb, Ke, Ki, Ve, Vi, AO);

    k_castW2<<<18432,256,0,stream>>>(wo, wao, Wb);
    k_gemmO<<<dim3(24,24),256,0,stream>>>(AO, Wb, (float*)d_out, bo, bao);
  } else {
    // ---------- fallback path (132.1 MB): 3 weight slots, groups sequential ----------
    unsigned short* Xh = (unsigned short*)alloc(12582912);
    unsigned short* Xe = (unsigned short*)alloc(6291456);
    unsigned short* Wb = (unsigned short*)alloc(56623104);  // 3 slots
    unsigned short* Qb = (unsigned short*)alloc(18874368);
    unsigned short* Ke = (unsigned short*)alloc(6291456);
    unsigned short* Ki = (unsigned short*)alloc(12582912);
    unsigned short* Ve = (unsigned short*)alloc(6291456);
    unsigned short* Vi = (unsigned short*)alloc(12582912);
    unsigned short* AO = Xh;

    k_cast<<<6144,256,0,stream>>>(hs, Xh, 1572864);
    k_cast<<<3072,256,0,stream>>>(ehs, Xe, 786432);

    k_cast<<<9216,256,0,stream>>>(wq, Wb, 2359296);
    k_cast<<<9216,256,0,stream>>>(wk, Wb + 9437184, 2359296);
    k_cast<<<9216,256,0,stream>>>(wv, Wb + 18874368, 2359296);
    k_gemmP<<<dim3(16,72),256,0,stream>>>(Xh, Wb, bq, bk, bv,
                                          nq, nk, rc, rs_, Qb, Ki, Vi, 1);

    k_cast<<<9216,256,0,stream>>>(waq, Wb, 2359296);
    k_cast<<<9216,256,0,stream>>>(wak, Wb + 9437184, 2359296);
    k_cast<<<9216,256,0,stream>>>(wav, Wb + 18874368, 2359296);
    k_gemmP<<<dim3(8,72),256,0,stream>>>(Xe, Wb, baq, bak, bav,
                                         naq, nak, rc, rs_, Qb, Ke, Ve, 0);

    k_attn<<<dim3(24,24,2),256,0,stream>>>(Qb, Ke, Ki, Ve, Vi, AO);

    k_castW2<<<18432,256,0,stream>>>(wo, wao, Wb);
    k_gemmO<<<dim3(24,24),256,0,stream>>>(AO, Wb, (float*)d_out, bo, bao);
  }
}